// Round 15
// baseline (260.499 us; speedup 1.0000x reference)
//
#include <hip/hip_runtime.h>
#include <hip/hip_bf16.h>
#include <math.h>

#define Bn 4096
#define Dd 768
#define SC2 28.85390081777927f   // 20 * log2(e): logits kept in base-2 domain
#define EPSF 1e-6f
#define DG 4.8516519541e8f       // expf(20.0f): exact exp_ori diagonal

// ws layout (4-byte elements)
#define O_S      0        // 3*4096 row sums (ori_nodiag, gen, aug)
#define O_SMOA   12288    // same-masked (ori_nodiag + aug) sums
#define O_SMG    16384    // same-masked gen sums
#define ZERO_F   20480    // floats to zero (covers all atomic sums)
#define O_P      20480    // uint: total pairs (= sum cnt^2)
#define O_RM     20608    // uint2[4096]: {tg | rank<<8, rowSlotBase}
#define LIST_OFF   262144      // byte offset: LCAP uint4 pair entries {row,x0,x1,x2}
#define LCAP       (1u << 19)
#define NB_OFF     33554432    // byte offset: bf16 normalized rows on|gn|an

typedef __attribute__((ext_vector_type(8))) short sh8;
typedef __attribute__((ext_vector_type(4))) float f32x4;

#define AS1 __attribute__((address_space(1)))
#define AS3 __attribute__((address_space(3)))

static __device__ __forceinline__ void gl_lds16(const void* g, void* l) {
    __builtin_amdgcn_global_load_lds((const AS1 void*)g, (AS3 void*)l, 16, 0, 0);
}

static __device__ __forceinline__ unsigned short f2b(float f) {
    unsigned int u = __float_as_uint(f);
    unsigned int r = (u + 0x7fffu + ((u >> 16) & 1u)) >> 16;  // RNE
    return (unsigned short)r;
}

// ---- normalize rows, write bf16 ----
__global__ void norm_kernel(const float* f0, const float* f1, const float* f2, unsigned short* nb) {
    int r = blockIdx.x, m = blockIdx.y, tid = threadIdx.x;
    const float* src = (m == 0 ? f0 : (m == 1 ? f1 : f2)) + (size_t)r * Dd;
    float x0 = src[tid], x1 = src[tid + 256], x2 = src[tid + 512];
    float v = x0 * x0 + x1 * x1 + x2 * x2;
    #pragma unroll
    for (int off = 1; off < 64; off <<= 1) v += __shfl_xor(v, off);
    __shared__ float wr[4];
    if ((tid & 63) == 0) wr[tid >> 6] = v;
    __syncthreads();
    float inv = rsqrtf(wr[0] + wr[1] + wr[2] + wr[3]);
    unsigned short* dst = nb + ((size_t)m * Bn + r) * Dd;
    dst[tid] = f2b(x0 * inv);
    dst[tid + 256] = f2b(x1 * inv);
    dst[tid + 512] = f2b(x2 * inv);
}

// ---- single-block: zero accumulators + class sort (hist/scan/rank+slot) ----
__launch_bounds__(1024)
__global__ void sort_kernel(const int* tg, unsigned int* I, float* out) {
    float* F = (float*)I;
    __shared__ unsigned int h[128], pb[128], cur[128];
    int tid = threadIdx.x;
    for (int e = tid; e < ZERO_F; e += 1024) F[e] = 0.f;
    if (tid == 0) { out[0] = 0.f; out[1] = 0.f; }
    if (tid < 128) { h[tid] = 0; cur[tid] = 0; }
    __syncthreads();
    for (int e = tid; e < Bn; e += 1024) atomicAdd(&h[tg[e]], 1u);
    __syncthreads();
    if (tid < 128) pb[tid] = h[tid] * h[tid];
    __syncthreads();
    for (int s = 1; s < 128; s <<= 1) {
        unsigned int b = 0;
        if (tid < 128 && tid >= s) b = pb[tid - s];
        __syncthreads();
        if (tid < 128) pb[tid] += b;
        __syncthreads();
    }
    if (tid == 127) I[O_P] = pb[127];
    uint2* RM = (uint2*)(I + O_RM);
    for (int e = tid; e < Bn; e += 1024) {
        int c = tg[e];
        unsigned int r = atomicAdd(&cur[c], 1u);
        unsigned int n = h[c];
        RM[e] = make_uint2((unsigned)c | (r << 8), (pb[c] - n * n) + r * n);
    }
}

// ---- fused GEMM + exp row-sum + masked sums + deterministic pair extraction.
// R14 base (BK=32, 128x128, swizzle pos=seg^((row>>1)&3) -> 0 conflicts,
// deterministic fire-and-forget pair slots, __launch_bounds__(256,4) ->
// VGPR 64+64acc = 128, 41% occupancy) + ONE change: double-buffered LDS,
// ONE barrier per K-iter. Loads for tile kt+1 issue right after the barrier
// and drain at the NEXT barrier -- a full compute phase in flight (R14's
// single-buffer drained them ~200cy after issue; load latency is 400-900cy,
// the dominant idle term at MfmaUtil 21%).
__launch_bounds__(256, 4)
__global__ void gemm_rowsum(const unsigned short* nb, char* ws) {
    float* F = (float*)ws;
    const unsigned int* I = (const unsigned int*)ws;
    const uint2* RM = (const uint2*)(I + O_RM);
    int z = blockIdx.z;
    const unsigned short* Ag = nb;
    const unsigned short* Bg = nb + (size_t)z * Bn * Dd;
    int m0 = blockIdx.y * 128, n0 = blockIdx.x * 128;
    int tid = threadIdx.x, lane = tid & 63, wave = tid >> 6;
    int wm = (wave >> 1) * 64, wn = (wave & 1) * 64;
    int lid = lane & 15, q = lane >> 4;
    __shared__ __align__(16) unsigned short Asm[2][128 * 32];
    __shared__ __align__(16) unsigned short Bsm[2][128 * 32];
    int c0 = tid, c1 = tid + 256;
    int row0 = c0 >> 2, sg0 = (c0 & 3) ^ ((row0 >> 1) & 3);
    int row1 = c1 >> 2, sg1 = (c1 & 3) ^ ((row1 >> 1) & 3);
    const unsigned short* gA0 = Ag + (size_t)(m0 + row0) * Dd + sg0 * 8;
    const unsigned short* gA1 = Ag + (size_t)(m0 + row1) * Dd + sg1 * 8;
    const unsigned short* gB0 = Bg + (size_t)(n0 + row0) * Dd + sg0 * 8;
    const unsigned short* gB1 = Bg + (size_t)(n0 + row1) * Dd + sg1 * 8;
    f32x4 acc[4][4] = {};
    // prologue: stage tile 0 into buffer 0
    gl_lds16(gA0, &Asm[0][c0 * 8]);
    gl_lds16(gA1, &Asm[0][c1 * 8]);
    gl_lds16(gB0, &Bsm[0][c0 * 8]);
    gl_lds16(gB1, &Bsm[0][c1 * 8]);
    #pragma unroll 4
    for (int kt = 0; kt < Dd / 32; ++kt) {
        int cur = kt & 1, nxt = cur ^ 1;
        __syncthreads();   // drains loads for tile kt (issued one compute-phase ago)
        if (kt + 1 < Dd / 32) {
            gl_lds16(gA0 + (kt + 1) * 32, &Asm[nxt][c0 * 8]);
            gl_lds16(gA1 + (kt + 1) * 32, &Asm[nxt][c1 * 8]);
            gl_lds16(gB0 + (kt + 1) * 32, &Bsm[nxt][c0 * 8]);
            gl_lds16(gB1 + (kt + 1) * 32, &Bsm[nxt][c1 * 8]);
        }
        sh8 af[4], bf[4];
        #pragma unroll
        for (int i = 0; i < 4; ++i) {
            int r = wm + i * 16 + lid;
            af[i] = *(const sh8*)&Asm[cur][r * 32 + ((q ^ ((r >> 1) & 3)) * 8)];
        }
        #pragma unroll
        for (int j = 0; j < 4; ++j) {
            int r = wn + j * 16 + lid;
            bf[j] = *(const sh8*)&Bsm[cur][r * 32 + ((q ^ ((r >> 1) & 3)) * 8)];
        }
        #pragma unroll
        for (int i = 0; i < 4; ++i)
            #pragma unroll
            for (int j = 0; j < 4; ++j)
                acc[i][j] = __builtin_amdgcn_mfma_f32_16x16x32_bf16(af[i], bf[j], acc[i][j], 0, 0, 0);
    }
    // ---- epilogue: row sum, masked sum, pair-list word stores ----
    uint2 rmc[4];
    #pragma unroll
    for (int j = 0; j < 4; ++j) rmc[j] = RM[n0 + wn + j * 16 + lid];
    int smoff = (z == 1) ? O_SMG : O_SMOA;
    unsigned int* Lw = (unsigned int*)(ws + LIST_OFF);
    #pragma unroll
    for (int i = 0; i < 4; ++i)
        #pragma unroll
        for (int reg = 0; reg < 4; ++reg) {
            int grow = m0 + wm + i * 16 + q * 4 + reg;
            uint2 rm = RM[grow];
            unsigned int trow = rm.x & 255u, rsb = rm.y;
            float rs = 0.f, ms = 0.f;
            #pragma unroll
            for (int j = 0; j < 4; ++j) {
                int gcol = n0 + wn + j * 16 + lid;
                float x = acc[i][j][reg] * SC2;
                float e = exp2f(x);
                if (z == 0 && gcol == grow) e = 0.f;
                rs += e;
                if ((rmc[j].x & 255u) == trow) {
                    ms += e;
                    unsigned int slot = rsb + (rmc[j].x >> 8);
                    if (slot < LCAP) {
                        if (z == 0) {
                            Lw[slot * 4 + 0] = (unsigned)grow;
                            Lw[slot * 4 + 1] = __float_as_uint(x);
                        } else {
                            Lw[slot * 4 + 1 + z] = __float_as_uint(x);
                        }
                    }
                }
            }
            #pragma unroll
            for (int off = 1; off < 16; off <<= 1) {
                rs += __shfl_xor(rs, off);
                ms += __shfl_xor(ms, off);
            }
            if (lid == 0) {
                atomicAdd(&F[O_S + z * Bn + grow], rs);
                atomicAdd(&F[smoff + grow], ms);
            }
        }
}

// ---- flat loss pass: inline denominators, scaled atomic into d_out ----
__launch_bounds__(256)
__global__ void loss_kernel(char* ws, float* out) {
    float* F = (float*)ws;
    const unsigned int* I = (const unsigned int*)ws;
    const uint4* L = (const uint4*)(ws + LIST_OFF);
    unsigned int n = I[O_P]; if (n > LCAP) n = LCAP;
    float a0 = 0.f, a1 = 0.f;
    unsigned int stride = gridDim.x * 256;
    for (unsigned int idx = blockIdx.x * 256 + threadIdx.x; idx < n; idx += stride) {
        uint4 en = L[idx];
        int i = (int)en.x;
        float son = F[O_S + i], sgen = F[O_S + Bn + i], saug = F[O_S + 2 * Bn + i];
        float dco = (son + saug - F[O_SMOA + i]) + sgen + EPSF;
        float dad = (sgen - F[O_SMG + i]) + saug + son + DG + EPSF;
        float eo = exp2f(__uint_as_float(en.y));
        float eg = exp2f(__uint_as_float(en.z));
        float ea = exp2f(__uint_as_float(en.w));
        a0 += -__logf(eg / (eg + dad) + EPSF);
        a1 += -__logf(eo / (eo + dco) + EPSF) - __logf(ea / (ea + dco) + EPSF);
    }
    #pragma unroll
    for (int off = 1; off < 64; off <<= 1) { a0 += __shfl_xor(a0, off); a1 += __shfl_xor(a1, off); }
    __shared__ float r0[4], r1[4];
    int tid = threadIdx.x;
    if ((tid & 63) == 0) { r0[tid >> 6] = a0; r1[tid >> 6] = a1; }
    __syncthreads();
    if (tid == 0) {
        atomicAdd(&out[0], (r0[0] + r0[1] + r0[2] + r0[3]) * (1.0f / Bn));  // ad_loss
        atomicAdd(&out[1], (r1[0] + r1[1] + r1[2] + r1[3]) * (1.0f / Bn));  // co_loss
    }
}

extern "C" void kernel_launch(void* const* d_in, const int* in_sizes, int n_in,
                              void* d_out, int out_size, void* d_ws, size_t ws_size,
                              hipStream_t stream) {
    const float* f0 = (const float*)d_in[0];
    const float* f1 = (const float*)d_in[1];
    const float* f2 = (const float*)d_in[2];
    const int* tg = (const int*)d_in[3];
    char* ws = (char*)d_ws;
    unsigned int* I = (unsigned int*)d_ws;
    unsigned short* nb = (unsigned short*)(ws + NB_OFF);
    float* out = (float*)d_out;

    norm_kernel<<<dim3(Bn, 3), 256, 0, stream>>>(f0, f1, f2, nb);
    sort_kernel<<<1, 1024, 0, stream>>>(tg, I, out);
    gemm_rowsum<<<dim3(32, 32, 3), 256, 0, stream>>>(nb, ws);
    loss_kernel<<<256, 256, 0, stream>>>(ws, out);
}

// Round 16
// 230.164 us; speedup vs baseline: 1.1318x; 1.1318x over previous
//
#include <hip/hip_runtime.h>
#include <hip/hip_bf16.h>
#include <math.h>

#define Bn 4096
#define Dd 768
#define SC2 28.85390081777927f   // 20 * log2(e): logits kept in base-2 domain
#define EPSF 1e-6f
#define DG 4.8516519541e8f       // expf(20.0f): exact exp_ori diagonal

// ws layout (4-byte elements)
#define O_S      0        // 3*4096 row sums (ori_nodiag, gen, aug)
#define O_SMOA   12288    // same-masked (ori_nodiag + aug) sums
#define O_SMG    16384    // same-masked gen sums
#define ZERO_F   20480    // floats to zero (covers all atomic sums)
#define O_P      20480    // uint: total pairs (= sum cnt^2)
#define O_RM     20608    // uint2[4096]: {tg | rank<<8, rowSlotBase}
#define LIST_OFF   262144      // byte offset: LCAP uint4 pair entries {row,x0,x1,x2}
#define LCAP       (1u << 19)
#define NB_OFF     33554432    // byte offset: bf16 normalized rows on|gn|an

typedef __attribute__((ext_vector_type(8))) short sh8;
typedef __attribute__((ext_vector_type(4))) float f32x4;

#define AS1 __attribute__((address_space(1)))
#define AS3 __attribute__((address_space(3)))

static __device__ __forceinline__ void gl_lds16(const void* g, void* l) {
    __builtin_amdgcn_global_load_lds((const AS1 void*)g, (AS3 void*)l, 16, 0, 0);
}

static __device__ __forceinline__ unsigned short f2b(float f) {
    unsigned int u = __float_as_uint(f);
    unsigned int r = (u + 0x7fffu + ((u >> 16) & 1u)) >> 16;  // RNE
    return (unsigned short)r;
}

// ---- normalize rows, write bf16 ----
__global__ void norm_kernel(const float* f0, const float* f1, const float* f2, unsigned short* nb) {
    int r = blockIdx.x, m = blockIdx.y, tid = threadIdx.x;
    const float* src = (m == 0 ? f0 : (m == 1 ? f1 : f2)) + (size_t)r * Dd;
    float x0 = src[tid], x1 = src[tid + 256], x2 = src[tid + 512];
    float v = x0 * x0 + x1 * x1 + x2 * x2;
    #pragma unroll
    for (int off = 1; off < 64; off <<= 1) v += __shfl_xor(v, off);
    __shared__ float wr[4];
    if ((tid & 63) == 0) wr[tid >> 6] = v;
    __syncthreads();
    float inv = rsqrtf(wr[0] + wr[1] + wr[2] + wr[3]);
    unsigned short* dst = nb + ((size_t)m * Bn + r) * Dd;
    dst[tid] = f2b(x0 * inv);
    dst[tid + 256] = f2b(x1 * inv);
    dst[tid + 512] = f2b(x2 * inv);
}

// ---- single-block: zero accumulators + class sort (hist/scan/rank+slot) ----
__launch_bounds__(1024)
__global__ void sort_kernel(const int* tg, unsigned int* I, float* out) {
    float* F = (float*)I;
    __shared__ unsigned int h[128], pb[128], cur[128];
    int tid = threadIdx.x;
    for (int e = tid; e < ZERO_F; e += 1024) F[e] = 0.f;
    if (tid == 0) { out[0] = 0.f; out[1] = 0.f; }
    if (tid < 128) { h[tid] = 0; cur[tid] = 0; }
    __syncthreads();
    for (int e = tid; e < Bn; e += 1024) atomicAdd(&h[tg[e]], 1u);
    __syncthreads();
    if (tid < 128) pb[tid] = h[tid] * h[tid];
    __syncthreads();
    for (int s = 1; s < 128; s <<= 1) {
        unsigned int b = 0;
        if (tid < 128 && tid >= s) b = pb[tid - s];
        __syncthreads();
        if (tid < 128) pb[tid] += b;
        __syncthreads();
    }
    if (tid == 127) I[O_P] = pb[127];
    uint2* RM = (uint2*)(I + O_RM);
    for (int e = tid; e < Bn; e += 1024) {
        int c = tg[e];
        unsigned int r = atomicAdd(&cur[c], 1u);
        unsigned int n = h[c];
        RM[e] = make_uint2((unsigned)c | (r << 8), (pb[c] - n * n) + r * n);
    }
}

#define COMPUTE_TILE(BUFA, BUFB) do {                                          \
    sh8 af[4], bf[4];                                                          \
    _Pragma("unroll")                                                          \
    for (int i = 0; i < 4; ++i) {                                              \
        int r = wm + i * 16 + lid;                                             \
        af[i] = *(const sh8*)&BUFA[r * 32 + ((q ^ ((r >> 1) & 3)) * 8)];       \
    }                                                                          \
    _Pragma("unroll")                                                          \
    for (int j = 0; j < 4; ++j) {                                              \
        int r = wn + j * 16 + lid;                                             \
        bf[j] = *(const sh8*)&BUFB[r * 32 + ((q ^ ((r >> 1) & 3)) * 8)];       \
    }                                                                          \
    _Pragma("unroll")                                                          \
    for (int i = 0; i < 4; ++i)                                                \
        _Pragma("unroll")                                                      \
        for (int j = 0; j < 4; ++j)                                            \
            acc[i][j] = __builtin_amdgcn_mfma_f32_16x16x32_bf16(af[i], bf[j], acc[i][j], 0, 0, 0); \
} while (0)

// ---- fused GEMM + exp row-sum + masked sums + deterministic pair extraction.
// R14 base (BK=32, 128x128, swizzle pos=seg^((row>>1)&3) -> 0 conflicts,
// deterministic fire-and-forget pair slots) + double-buffered LDS ping-pong,
// ONE barrier per tile, SPILL-FREE this time: __launch_bounds__(256,3)
// (170-reg budget; R15's hard 128 cap spilled the dbuf addressing to scratch
// -- WRITE_SIZE 38->93MB -- masking the pipelining effect entirely).
// Manual 2x unroll with named buffers avoids cur/nxt index registers.
__launch_bounds__(256, 3)
__global__ void gemm_rowsum(const unsigned short* nb, char* ws) {
    float* F = (float*)ws;
    const unsigned int* I = (const unsigned int*)ws;
    const uint2* RM = (const uint2*)(I + O_RM);
    int z = blockIdx.z;
    const unsigned short* Ag = nb;
    const unsigned short* Bg = nb + (size_t)z * Bn * Dd;
    int m0 = blockIdx.y * 128, n0 = blockIdx.x * 128;
    int tid = threadIdx.x, lane = tid & 63, wave = tid >> 6;
    int wm = (wave >> 1) * 64, wn = (wave & 1) * 64;
    int lid = lane & 15, q = lane >> 4;
    __shared__ __align__(16) unsigned short Asm0[128 * 32], Asm1[128 * 32];
    __shared__ __align__(16) unsigned short Bsm0[128 * 32], Bsm1[128 * 32];
    int c0 = tid, c1 = tid + 256;
    int row0 = c0 >> 2, sg0 = (c0 & 3) ^ ((row0 >> 1) & 3);
    int row1 = c1 >> 2, sg1 = (c1 & 3) ^ ((row1 >> 1) & 3);
    const unsigned short* gA0 = Ag + (size_t)(m0 + row0) * Dd + sg0 * 8;
    const unsigned short* gA1 = Ag + (size_t)(m0 + row1) * Dd + sg1 * 8;
    const unsigned short* gB0 = Bg + (size_t)(n0 + row0) * Dd + sg0 * 8;
    const unsigned short* gB1 = Bg + (size_t)(n0 + row1) * Dd + sg1 * 8;
    f32x4 acc[4][4] = {};
    // prologue: tile 0 -> buffer 0
    gl_lds16(gA0, &Asm0[c0 * 8]);
    gl_lds16(gA1, &Asm0[c1 * 8]);
    gl_lds16(gB0, &Bsm0[c0 * 8]);
    gl_lds16(gB1, &Bsm0[c1 * 8]);
    for (int kt2 = 0; kt2 < Dd / 64; ++kt2) {
        int t1 = kt2 * 2 + 1, t2 = kt2 * 2 + 2;
        __syncthreads();                       // drains tile 2*kt2 (issued one compute-phase ago)
        gl_lds16(gA0 + t1 * 32, &Asm1[c0 * 8]);
        gl_lds16(gA1 + t1 * 32, &Asm1[c1 * 8]);
        gl_lds16(gB0 + t1 * 32, &Bsm1[c0 * 8]);
        gl_lds16(gB1 + t1 * 32, &Bsm1[c1 * 8]);
        COMPUTE_TILE(Asm0, Bsm0);
        __syncthreads();                       // drains tile t1
        if (t2 < Dd / 32) {
            gl_lds16(gA0 + t2 * 32, &Asm0[c0 * 8]);
            gl_lds16(gA1 + t2 * 32, &Asm0[c1 * 8]);
            gl_lds16(gB0 + t2 * 32, &Bsm0[c0 * 8]);
            gl_lds16(gB1 + t2 * 32, &Bsm0[c1 * 8]);
        }
        COMPUTE_TILE(Asm1, Bsm1);
    }
    // ---- epilogue: row sum, masked sum, pair-list word stores ----
    uint2 rmc[4];
    #pragma unroll
    for (int j = 0; j < 4; ++j) rmc[j] = RM[n0 + wn + j * 16 + lid];
    int smoff = (z == 1) ? O_SMG : O_SMOA;
    unsigned int* Lw = (unsigned int*)(ws + LIST_OFF);
    #pragma unroll
    for (int i = 0; i < 4; ++i)
        #pragma unroll
        for (int reg = 0; reg < 4; ++reg) {
            int grow = m0 + wm + i * 16 + q * 4 + reg;
            uint2 rm = RM[grow];
            unsigned int trow = rm.x & 255u, rsb = rm.y;
            float rs = 0.f, ms = 0.f;
            #pragma unroll
            for (int j = 0; j < 4; ++j) {
                int gcol = n0 + wn + j * 16 + lid;
                float x = acc[i][j][reg] * SC2;
                float e = exp2f(x);
                if (z == 0 && gcol == grow) e = 0.f;
                rs += e;
                if ((rmc[j].x & 255u) == trow) {
                    ms += e;
                    unsigned int slot = rsb + (rmc[j].x >> 8);
                    if (slot < LCAP) {
                        if (z == 0) {
                            Lw[slot * 4 + 0] = (unsigned)grow;
                            Lw[slot * 4 + 1] = __float_as_uint(x);
                        } else {
                            Lw[slot * 4 + 1 + z] = __float_as_uint(x);
                        }
                    }
                }
            }
            #pragma unroll
            for (int off = 1; off < 16; off <<= 1) {
                rs += __shfl_xor(rs, off);
                ms += __shfl_xor(ms, off);
            }
            if (lid == 0) {
                atomicAdd(&F[O_S + z * Bn + grow], rs);
                atomicAdd(&F[smoff + grow], ms);
            }
        }
}

// ---- flat loss pass: inline denominators, scaled atomic into d_out ----
__launch_bounds__(256)
__global__ void loss_kernel(char* ws, float* out) {
    float* F = (float*)ws;
    const unsigned int* I = (const unsigned int*)ws;
    const uint4* L = (const uint4*)(ws + LIST_OFF);
    unsigned int n = I[O_P]; if (n > LCAP) n = LCAP;
    float a0 = 0.f, a1 = 0.f;
    unsigned int stride = gridDim.x * 256;
    for (unsigned int idx = blockIdx.x * 256 + threadIdx.x; idx < n; idx += stride) {
        uint4 en = L[idx];
        int i = (int)en.x;
        float son = F[O_S + i], sgen = F[O_S + Bn + i], saug = F[O_S + 2 * Bn + i];
        float dco = (son + saug - F[O_SMOA + i]) + sgen + EPSF;
        float dad = (sgen - F[O_SMG + i]) + saug + son + DG + EPSF;
        float eo = exp2f(__uint_as_float(en.y));
        float eg = exp2f(__uint_as_float(en.z));
        float ea = exp2f(__uint_as_float(en.w));
        a0 += -__logf(eg / (eg + dad) + EPSF);
        a1 += -__logf(eo / (eo + dco) + EPSF) - __logf(ea / (ea + dco) + EPSF);
    }
    #pragma unroll
    for (int off = 1; off < 64; off <<= 1) { a0 += __shfl_xor(a0, off); a1 += __shfl_xor(a1, off); }
    __shared__ float r0[4], r1[4];
    int tid = threadIdx.x;
    if ((tid & 63) == 0) { r0[tid >> 6] = a0; r1[tid >> 6] = a1; }
    __syncthreads();
    if (tid == 0) {
        atomicAdd(&out[0], (r0[0] + r0[1] + r0[2] + r0[3]) * (1.0f / Bn));  // ad_loss
        atomicAdd(&out[1], (r1[0] + r1[1] + r1[2] + r1[3]) * (1.0f / Bn));  // co_loss
    }
}

extern "C" void kernel_launch(void* const* d_in, const int* in_sizes, int n_in,
                              void* d_out, int out_size, void* d_ws, size_t ws_size,
                              hipStream_t stream) {
    const float* f0 = (const float*)d_in[0];
    const float* f1 = (const float*)d_in[1];
    const float* f2 = (const float*)d_in[2];
    const int* tg = (const int*)d_in[3];
    char* ws = (char*)d_ws;
    unsigned int* I = (unsigned int*)d_ws;
    unsigned short* nb = (unsigned short*)(ws + NB_OFF);
    float* out = (float*)d_out;

    norm_kernel<<<dim3(Bn, 3), 256, 0, stream>>>(f0, f1, f2, nb);
    sort_kernel<<<1, 1024, 0, stream>>>(tg, I, out);
    gemm_rowsum<<<dim3(32, 32, 3), 256, 0, stream>>>(nb, ws);
    loss_kernel<<<256, 256, 0, stream>>>(ws, out);
}